// Round 1
// baseline (211.266 us; speedup 1.0000x reference)
//
#include <hip/hip_runtime.h>
#include <hip/hip_bf16.h>

// OuterMean: algebraic collapse.
// out[i,j,d] = L[i,d] + R[j,d], where
//   S[i,d] = mean_m LN(x)[m,i,d]                    (LN over last dim, eps 1e-5)
//   L = (S @ w_left  + b_left ) @ w_out
//   R = (S @ w_right + b_right) @ w_out + b_out
//
// Workspace layout (floats): S[0:65536], L[65536:131072], R[131072:196608]

#define DIM 128
#define NI  512
#define NM  256

// ---------------- Kernel 1: LayerNorm + mean over m -> S (512 x 128) --------
// One block per i. 512 threads = 8 waves; wave w handles m = w, w+8, ..., w+248.
// Each lane holds 2 consecutive d (float2): 64 lanes x 8B = full 512B row, coalesced.
__global__ __launch_bounds__(512) void ln_mean_kernel(
    const float* __restrict__ x,
    const float* __restrict__ ln_g,
    const float* __restrict__ ln_b,
    float* __restrict__ S)
{
    const int i    = blockIdx.x;      // 0..511
    const int tid  = threadIdx.x;     // 0..511
    const int lane = tid & 63;
    const int wave = tid >> 6;        // 0..7

    const float g0  = ln_g[2*lane];
    const float g1  = ln_g[2*lane + 1];
    const float be0 = ln_b[2*lane];
    const float be1 = ln_b[2*lane + 1];

    float acc0 = 0.f, acc1 = 0.f;

    #pragma unroll 4
    for (int t = 0; t < NM/8; ++t) {
        const int m = wave + (t << 3);
        const float2 v = *(const float2*)(x + (((size_t)(m * NI + i)) << 7) + 2*lane);

        float s  = v.x + v.y;
        float s2 = v.x*v.x + v.y*v.y;
        #pragma unroll
        for (int off = 32; off; off >>= 1) {
            s  += __shfl_xor(s,  off);
            s2 += __shfl_xor(s2, off);
        }
        const float mu   = s * (1.f/128.f);
        const float var  = s2 * (1.f/128.f) - mu*mu;
        const float rstd = rsqrtf(var + 1e-5f);

        acc0 += (v.x - mu) * rstd * g0 + be0;
        acc1 += (v.y - mu) * rstd * g1 + be1;
    }

    __shared__ float red0[512];
    __shared__ float red1[512];
    red0[tid] = acc0;
    red1[tid] = acc1;
    __syncthreads();

    if (tid < 64) {
        float a0 = 0.f, a1 = 0.f;
        #pragma unroll
        for (int w = 0; w < 8; ++w) {
            a0 += red0[(w << 6) + tid];
            a1 += red1[(w << 6) + tid];
        }
        float2 r;
        r.x = a0 * (1.f/(float)NM);
        r.y = a1 * (1.f/(float)NM);
        *(float2*)(S + ((size_t)i << 7) + 2*tid) = r;
    }
}

// ---------------- Kernel 2: per-row chain S -> L,R (each 512 x 128) ---------
// One block per i, 256 threads. Threads 0..127 do the left path, 128..255 right.
// Stage 1: T[h] = sum_d S[i,d] * W[d,h] + bias[h]   (W is (DIM,HID) row-major)
// Stage 2: out[d] = sum_h T[h] * w_out[h,d]  (+ b_out for right path)
__global__ __launch_bounds__(256) void project_kernel(
    const float* __restrict__ S,
    const float* __restrict__ w_left,  const float* __restrict__ b_left,
    const float* __restrict__ w_right, const float* __restrict__ b_right,
    const float* __restrict__ w_out,   const float* __restrict__ b_out,
    float* __restrict__ L, float* __restrict__ R)
{
    const int i   = blockIdx.x;
    const int tid = threadIdx.x;
    const int h   = tid & 127;
    const bool isR = (tid >= 128);

    __shared__ float sS[128];
    __shared__ float sTL[128];
    __shared__ float sTR[128];

    if (tid < 128) sS[tid] = S[((size_t)i << 7) + tid];
    __syncthreads();

    const float* W = isR ? w_right : w_left;
    float acc = isR ? b_right[h] : b_left[h];
    #pragma unroll 8
    for (int d = 0; d < DIM; ++d) {
        acc += sS[d] * W[(d << 7) + h];   // sS[d] broadcast; W coalesced
    }
    (isR ? sTR : sTL)[h] = acc;
    __syncthreads();

    const float* T = isR ? sTR : sTL;
    float acc2 = isR ? b_out[h] : 0.f;    // fold b_out into R
    #pragma unroll 8
    for (int hh = 0; hh < DIM; ++hh) {
        acc2 += T[hh] * w_out[(hh << 7) + h];
    }
    (isR ? R : L)[((size_t)i << 7) + h] = acc2;
}

// ---------------- Kernel 3: out[i,j,d] = L[i,d] + R[j,d] --------------------
// 512*512*128 floats = 8,388,608 float4 stores. Pure streaming write.
__global__ __launch_bounds__(256) void expand_kernel(
    const float4* __restrict__ L4,
    const float4* __restrict__ R4,
    float4* __restrict__ out4)
{
    const size_t t = (size_t)blockIdx.x * 256 + threadIdx.x;  // 0..8388607
    const int d4 = (int)(t & 31);
    const int j  = (int)((t >> 5) & 511);
    const int i  = (int)(t >> 14);

    const float4 a = L4[(i << 5) + d4];
    const float4 b = R4[(j << 5) + d4];
    float4 o;
    o.x = a.x + b.x;
    o.y = a.y + b.y;
    o.z = a.z + b.z;
    o.w = a.w + b.w;
    out4[t] = o;
}

extern "C" void kernel_launch(void* const* d_in, const int* in_sizes, int n_in,
                              void* d_out, int out_size, void* d_ws, size_t ws_size,
                              hipStream_t stream) {
    const float* x       = (const float*)d_in[0];
    const float* ln_g    = (const float*)d_in[1];
    const float* ln_b    = (const float*)d_in[2];
    const float* w_left  = (const float*)d_in[3];
    const float* b_left  = (const float*)d_in[4];
    const float* w_right = (const float*)d_in[5];
    const float* b_right = (const float*)d_in[6];
    const float* w_out   = (const float*)d_in[7];
    const float* b_out   = (const float*)d_in[8];

    float* S = (float*)d_ws;            // 512*128
    float* L = S + NI * DIM;            // 512*128
    float* R = L + NI * DIM;            // 512*128

    ln_mean_kernel<<<NI, 512, 0, stream>>>(x, ln_g, ln_b, S);
    project_kernel<<<NI, 256, 0, stream>>>(S, w_left, b_left, w_right, b_right,
                                           w_out, b_out, L, R);

    const int total4 = NI * NI * (DIM / 4);          // 8,388,608
    expand_kernel<<<total4 / 256, 256, 0, stream>>>((const float4*)L,
                                                    (const float4*)R,
                                                    (float4*)d_out);
}